// Round 9
// baseline (878.788 us; speedup 1.0000x reference)
//
#include <hip/hip_runtime.h>
#include <cstdint>
#include <cstddef>

// ---------------------------------------------------------------------------
// GatedGIN forward. Inputs bf16-or-f32 (runtime probe), OUTPUT = FLOAT32.
// Round 20: k_mm12h col-split (gru8 trick). Round-8 taught: time ~ per-wave
// weight-load count. Now each wave owns 32 output COLS: weights loaded once
// per phase (8 frags/wave = zero redundancy, 4x less than r7, 8x less than
// r8); A staged to LDS once and shared. Row-norm via cross-wave ssq buffer.
// Phase 4: 2 threads/row over 128 rows. spmm unroll-8, gru8 unchanged.
// ---------------------------------------------------------------------------

typedef short  v8s __attribute__((ext_vector_type(8)));
typedef float  v4f __attribute__((ext_vector_type(4)));

#define BUCKET_CAP 4096

static __device__ __forceinline__ float bf2f(uint16_t u) {
  return __uint_as_float(((uint32_t)u) << 16);
}
static __device__ __forceinline__ uint16_t f2b(float f) {
  uint32_t x = __float_as_uint(f);
  return (uint16_t)((x + 0x7FFFu + ((x >> 16) & 1u)) >> 16);
}
static __device__ __forceinline__ float sigmoidf_(float v) {
  return 1.f / (1.f + __expf(-v));
}
static __device__ __forceinline__ float tanhf_(float v) {
  return 1.f - 2.f / (__expf(2.f * v) + 1.f);
}

// ---------------- dtype probe ----------------
__global__ void k_detect(const uint32_t* __restrict__ u, int* __restrict__ flag) {
  int lane = threadIdx.x;  // 64 threads
  uint32_t low = u[lane] & 0xFFFFu;
  uint32_t e = (low >> 7) & 0xFFu;
  bool pass = (e == 0) || (e >= 110 && e <= 141);
  unsigned long long b = __ballot(pass);
  if (lane == 0) *flag = (__popcll(b) >= 32) ? 1 : 0;
}

// ---------------- weight convert: one pass -> f32 arena + bf16 arena -------
struct CvtDesc {
  const void* src[18];
  int off[19];
};

__global__ void k_cvtw(CvtDesc c, float* __restrict__ wbase,
                       uint16_t* __restrict__ wb16,
                       const int* __restrict__ flag, int total) {
  int gid = blockIdx.x * 256 + threadIdx.x;
  if (gid >= total) return;
  int t = 0;
#pragma unroll
  for (int i = 1; i < 18; i++)
    if (gid >= c.off[i]) t = i;
  int local = gid - c.off[t];
  float v;
  if (*flag) v = bf2f(((const uint16_t*)c.src[t])[local]);
  else       v = ((const float*)c.src[t])[local];
  wbase[gid] = v;
  wb16[gid] = f2b(v);
}

__global__ void k_cvt_feat(const void* __restrict__ src, uint16_t* __restrict__ dst,
                           int n, const int* __restrict__ flag) {
  int i = blockIdx.x * 256 + threadIdx.x;
  if (i >= n) return;
  if (*flag) dst[i] = ((const uint16_t*)src)[i];
  else       dst[i] = f2b(((const float*)src)[i]);
}

__global__ void k_zero_i(int* __restrict__ p, int n) {
  int i = blockIdx.x * 256 + threadIdx.x;
  if (i < n) p[i] = 0;
}

__global__ void k_zero_f(float* __restrict__ p, int n) {
  int i = blockIdx.x * 256 + threadIdx.x;
  if (i < n) p[i] = 0.f;
}

// ---------------- weight repack: fragment-major for 16x16x32 MFMA ----------
__global__ void k_pack_mm(const uint16_t* __restrict__ src, uint16_t* __restrict__ dst,
                          int nmat) {
  int id = blockIdx.x * 256 + threadIdx.x;
  if (id >= nmat * 2048) return;
  int mat = id >> 11;
  int rem = id & 2047;
  int blk = rem >> 6, lane = rem & 63;
  int kc = blk >> 3, t = blk & 7;
  int n0 = lane & 15, quad = lane >> 4;
  const uint16_t* s = src + (size_t)mat * 16384 + (size_t)(t * 16 + n0) * 128 + kc * 32 + quad * 8;
  uint16_t* d = dst + (size_t)id * 8;
  *reinterpret_cast<v8s*>(d) = *reinterpret_cast<const v8s*>(s);
}

// GRU layout: blk = (kc*4 + s)*12 + (u*2 + mat)*3 + g  (192 blocks/layer)
__global__ void k_pack_gru(const uint16_t* __restrict__ wih, const uint16_t* __restrict__ whh,
                           uint16_t* __restrict__ dst, int nlayer) {
  int id = blockIdx.x * 256 + threadIdx.x;
  if (id >= nlayer * 192 * 64) return;
  int lane = id & 63;
  int blk = (id >> 6) % 192;
  int layer = (id >> 6) / 192;
  int g = blk % 3;
  int mat = (blk / 3) % 2;
  int u = (blk / 6) % 2;
  int w = (blk / 12) % 4;
  int kc = blk / 48;
  int n0 = lane & 15, quad = lane >> 4;
  const uint16_t* base = (mat == 0 ? wih : whh) + (size_t)layer * 384 * 128;
  const uint16_t* s = base + (size_t)(g * 128 + w * 32 + u * 16 + n0) * 128 + kc * 32 + quad * 8;
  uint16_t* d = dst + ((size_t)layer * 192 + blk) * 512 + (size_t)lane * 8;
  *reinterpret_cast<v8s*>(d) = *reinterpret_cast<const v8s*>(s);
}

// ---------------- CSR build: chunk-reserved bucket partition ----------------
__global__ void k_part(const int* __restrict__ dst, const int* __restrict__ src,
                       const void* __restrict__ w, int* __restrict__ gcur,
                       uint2* __restrict__ ep0, const int* __restrict__ flag,
                       int E, int NB) {
  __shared__ int hist[1024];
  __shared__ int lbase[1024];
  int t = threadIdx.x;
  int CH = (E + gridDim.x - 1) / gridDim.x;
  int e0 = blockIdx.x * CH;
  int e1 = e0 + CH;
  if (e1 > E) e1 = E;
  for (int b = t; b < NB; b += 256) hist[b] = 0;
  __syncthreads();
  for (int e = e0 + t; e < e1; e += 256)
    atomicAdd(&hist[dst[e] >> 7], 1);
  __syncthreads();
  for (int b = t; b < NB; b += 256) {
    int c = hist[b];
    lbase[b] = c ? atomicAdd(&gcur[b], c) : 0;
    hist[b] = 0;  // becomes local cursor
  }
  __syncthreads();
  bool bf = (*flag) != 0;
  for (int e = e0 + t; e < e1; e += 256) {
    int d = dst[e];
    int b = d >> 7;
    int pos = lbase[b] + atomicAdd(&hist[b], 1);
    if (pos >= BUCKET_CAP) pos = BUCKET_CAP - 1;  // safety, never on bench input
    float wv = bf ? bf2f(((const uint16_t*)w)[e]) : ((const float*)w)[e];
    ep0[(size_t)b * BUCKET_CAP + pos] =
        make_uint2((uint32_t)src[e] | (((uint32_t)d & 127u) << 25),
                   __float_as_uint(wv));
  }
}

// exclusive scan over per-bucket totals -> bbase[NB] (single block)
__global__ void k_bprefix(const int* __restrict__ gcur, int* __restrict__ bbase,
                          int nbuckets) {
  __shared__ int red[256];
  int t = threadIdx.x;
  int chunk = (nbuckets + 255) >> 8;
  int beg = t * chunk;
  int end = beg + chunk;
  if (end > nbuckets) end = nbuckets;
  int s = 0;
  for (int b = beg; b < end; b++) {
    int c = gcur[b];
    if (c > BUCKET_CAP) c = BUCKET_CAP;
    bbase[b] = c;  // temp: per-bucket total
    s += c;
  }
  red[t] = s;
  __syncthreads();
  for (int off = 1; off < 256; off <<= 1) {
    int u = (t >= off) ? red[t - off] : 0;
    __syncthreads();
    red[t] += u;
    __syncthreads();
  }
  int run = red[t] - s;
  for (int b = beg; b < end; b++) {
    int tot = bbase[b];
    bbase[b] = run;
    run += tot;
  }
}

// one block per bucket: LDS histogram of local dst -> rowptr slice + place
__global__ void k_build(const uint2* __restrict__ ep0, const int* __restrict__ gcur,
                        const int* __restrict__ bbase, int* __restrict__ rowptr,
                        uint2* __restrict__ ep, int n, int nbuckets) {
  __shared__ int lcnt[128];
  __shared__ int lsc[128];
  int b = blockIdx.x, t = threadIdx.x;
  int cnt = gcur[b];
  if (cnt > BUCKET_CAP) cnt = BUCKET_CAP;
  if (t < 128) lcnt[t] = 0;
  __syncthreads();

  const uint2* sp = ep0 + (size_t)b * BUCKET_CAP;
  // pass 1: histogram local dst
  for (int p = t; p < cnt; p += 256)
    atomicAdd(&lcnt[sp[p].x >> 25], 1);
  __syncthreads();

  // inclusive scan of lcnt -> lsc
  if (t < 128) lsc[t] = lcnt[t];
  __syncthreads();
  for (int off = 1; off < 128; off <<= 1) {
    int v = 0;
    if (t < 128 && t >= off) v = lsc[t - off];
    __syncthreads();
    if (t < 128) lsc[t] += v;
    __syncthreads();
  }

  int base = bbase[b];
  if (t < 128) {
    int excl = lsc[t] - lcnt[t];
    int node = b * 128 + t;
    if (node < n) rowptr[node] = base + excl;
    lcnt[t] = base + excl;  // becomes cursor
  }
  if (b == nbuckets - 1 && t == 0) rowptr[n] = base + lsc[127];  // == E
  __syncthreads();

  // pass 2: place edges at exact CSR positions (contiguous output region)
  for (int p = t; p < cnt; p += 256) {
    uint2 v = sp[p];
    int pos = atomicAdd(&lcnt[v.x >> 25], 1);
    ep[pos] = make_uint2(v.x & 0x01FFFFFFu, v.y);
  }
}

// ---------------- SpMM gather: 4 nodes/block, 64 thr/node, unroll 8 --------
__global__ void k_spmm(const uint16_t* __restrict__ x, const int* __restrict__ rowptr,
                       const uint2* __restrict__ ep, uint16_t* __restrict__ agg, int n) {
  int node = blockIdx.x * 4 + (threadIdx.x >> 6);
  int lane = threadIdx.x & 63;
  if (node >= n) return;
  int p0 = rowptr[node], p1 = rowptr[node + 1];
  float a0 = 0.f, a1 = 0.f;
  const uint16_t* xc = x + (size_t)lane * 2;
  int p = p0;
  for (; p + 7 < p1; p += 8) {
    uint2 e0 = ep[p], e1 = ep[p + 1], e2 = ep[p + 2], e3 = ep[p + 3];
    uint2 e4 = ep[p + 4], e5 = ep[p + 5], e6 = ep[p + 6], e7 = ep[p + 7];
    uint32_t u0 = *reinterpret_cast<const uint32_t*>(xc + (size_t)e0.x * 128);
    uint32_t u1 = *reinterpret_cast<const uint32_t*>(xc + (size_t)e1.x * 128);
    uint32_t u2 = *reinterpret_cast<const uint32_t*>(xc + (size_t)e2.x * 128);
    uint32_t u3 = *reinterpret_cast<const uint32_t*>(xc + (size_t)e3.x * 128);
    uint32_t u4 = *reinterpret_cast<const uint32_t*>(xc + (size_t)e4.x * 128);
    uint32_t u5 = *reinterpret_cast<const uint32_t*>(xc + (size_t)e5.x * 128);
    uint32_t u6 = *reinterpret_cast<const uint32_t*>(xc + (size_t)e6.x * 128);
    uint32_t u7 = *reinterpret_cast<const uint32_t*>(xc + (size_t)e7.x * 128);
    float w0 = __uint_as_float(e0.y), w1 = __uint_as_float(e1.y);
    float w2 = __uint_as_float(e2.y), w3 = __uint_as_float(e3.y);
    float w4 = __uint_as_float(e4.y), w5 = __uint_as_float(e5.y);
    float w6 = __uint_as_float(e6.y), w7 = __uint_as_float(e7.y);
    a0 = fmaf(w0, bf2f((uint16_t)u0), a0);
    a1 = fmaf(w0, bf2f((uint16_t)(u0 >> 16)), a1);
    a0 = fmaf(w1, bf2f((uint16_t)u1), a0);
    a1 = fmaf(w1, bf2f((uint16_t)(u1 >> 16)), a1);
    a0 = fmaf(w2, bf2f((uint16_t)u2), a0);
    a1 = fmaf(w2, bf2f((uint16_t)(u2 >> 16)), a1);
    a0 = fmaf(w3, bf2f((uint16_t)u3), a0);
    a1 = fmaf(w3, bf2f((uint16_t)(u3 >> 16)), a1);
    a0 = fmaf(w4, bf2f((uint16_t)u4), a0);
    a1 = fmaf(w4, bf2f((uint16_t)(u4 >> 16)), a1);
    a0 = fmaf(w5, bf2f((uint16_t)u5), a0);
    a1 = fmaf(w5, bf2f((uint16_t)(u5 >> 16)), a1);
    a0 = fmaf(w6, bf2f((uint16_t)u6), a0);
    a1 = fmaf(w6, bf2f((uint16_t)(u6 >> 16)), a1);
    a0 = fmaf(w7, bf2f((uint16_t)u7), a0);
    a1 = fmaf(w7, bf2f((uint16_t)(u7 >> 16)), a1);
  }
  for (; p + 1 < p1; p += 2) {
    uint2 e0 = ep[p], e1 = ep[p + 1];
    uint32_t u0 = *reinterpret_cast<const uint32_t*>(xc + (size_t)e0.x * 128);
    uint32_t u1 = *reinterpret_cast<const uint32_t*>(xc + (size_t)e1.x * 128);
    float w0 = __uint_as_float(e0.y), w1 = __uint_as_float(e1.y);
    a0 = fmaf(w0, bf2f((uint16_t)u0), a0);
    a1 = fmaf(w0, bf2f((uint16_t)(u0 >> 16)), a1);
    a0 = fmaf(w1, bf2f((uint16_t)u1), a0);
    a1 = fmaf(w1, bf2f((uint16_t)(u1 >> 16)), a1);
  }
  for (; p < p1; p++) {
    uint2 e0 = ep[p];
    float w0 = __uint_as_float(e0.y);
    uint32_t u0 = *reinterpret_cast<const uint32_t*>(xc + (size_t)e0.x * 128);
    a0 = fmaf(w0, bf2f((uint16_t)u0), a0);
    a1 = fmaf(w0, bf2f((uint16_t)(u0 >> 16)), a1);
  }
  uint32_t packed = (uint32_t)f2b(a0) | ((uint32_t)f2b(a1) << 16);
  *reinterpret_cast<uint32_t*>(agg + (size_t)node * 128 + lane * 2) = packed;
}

// ---------------- MFMA matmul, repacked W, 32 rows/wave ----------
// EPI 1 = relu. Out bf16. Block = 4 waves = 128 rows.
template <int EPI>
__launch_bounds__(256)
__global__ void k_mm(const uint16_t* __restrict__ A, const uint16_t* __restrict__ Wrp,
                     const float* __restrict__ bias, uint16_t* __restrict__ C,
                     int nrows) {
  int wave = threadIdx.x >> 6, lane = threadIdx.x & 63;
  int n0 = lane & 15, quad = lane >> 4;
  int m0 = (blockIdx.x * 4 + wave) * 32;
  int r0 = m0 + n0, r1 = m0 + 16 + n0;
  bool ok0 = r0 < nrows, ok1 = r1 < nrows;
  const v8s z8 = {0, 0, 0, 0, 0, 0, 0, 0};

  v4f acc[2][8];
#pragma unroll
  for (int rt = 0; rt < 2; rt++)
#pragma unroll
    for (int t = 0; t < 8; t++) acc[rt][t] = {0.f, 0.f, 0.f, 0.f};

  const uint16_t* ap0 = A + (size_t)r0 * 128 + quad * 8;
  const uint16_t* ap1 = A + (size_t)r1 * 128 + quad * 8;
#pragma unroll
  for (int kc = 0; kc < 4; kc++) {
    v8s a0 = ok0 ? *reinterpret_cast<const v8s*>(ap0 + kc * 32) : z8;
    v8s a1 = ok1 ? *reinterpret_cast<const v8s*>(ap1 + kc * 32) : z8;
    const uint16_t* wp = Wrp + (size_t)kc * 4096 + (size_t)lane * 8;
#pragma unroll
    for (int t = 0; t < 8; t++) {
      v8s bf = *reinterpret_cast<const v8s*>(wp + t * 512);
      acc[0][t] = __builtin_amdgcn_mfma_f32_16x16x32_bf16(a0, bf, acc[0][t], 0, 0, 0);
      acc[1][t] = __builtin_amdgcn_mfma_f32_16x16x32_bf16(a1, bf, acc[1][t], 0, 0, 0);
    }
  }

#pragma unroll
  for (int rt = 0; rt < 2; rt++) {
    int mb = m0 + rt * 16;
    float vv[8][4];
#pragma unroll
    for (int t = 0; t < 8; t++) {
      float b = bias[t * 16 + n0];
#pragma unroll
      for (int r = 0; r < 4; r++) vv[t][r] = fmaxf(acc[rt][t][r] + b, 0.f);
    }
    if (EPI == 2) {
#pragma unroll
      for (int r = 0; r < 4; r++) {
        float ss = 0.f;
#pragma unroll
        for (int t = 0; t < 8; t++) ss = fmaf(vv[t][r], vv[t][r], ss);
        ss += __shfl_xor(ss, 1);
        ss += __shfl_xor(ss, 2);
        ss += __shfl_xor(ss, 4);
        ss += __shfl_xor(ss, 8);
        float sc = rsqrtf(1.f + ss);
#pragma unroll
        for (int t = 0; t < 8; t++) vv[t][r] *= sc;
      }
    }
#pragma unroll
    for (int r = 0; r < 4; r++) {
      int row = mb + quad * 4 + r;
      if (row >= nrows) continue;
#pragma unroll
      for (int t = 0; t < 8; t++)
        C[(size_t)row * 128 + t * 16 + n0] = f2b(vv[t][r]);
    }
  }
}

// ---------------- fused GIN mlp1+mlp2+norm + head mlp + heads (col-split) --
// 128 rows/block; each wave owns 32 output cols (t = wave*2, wave*2+1).
// Stage A rows -> LDS once; per phase each wave loads only ITS 8 weight
// fragments (zero redundancy), A-frags via ds_read. Row-norm: per-wave
// partial (shfl tree) -> ssq[128][4] -> combine. Phase 4: 2 threads/row.
template <int C>
__launch_bounds__(256)
__global__ void k_mm12h(const uint16_t* __restrict__ A,
                        const uint16_t* __restrict__ W1rp, const float* __restrict__ b1,
                        const uint16_t* __restrict__ W2rp, const float* __restrict__ b2,
                        const uint16_t* __restrict__ Whrp, const float* __restrict__ bh,
                        const float* __restrict__ w2, const float* __restrict__ b2h,
                        uint16_t* __restrict__ xbout,
                        float* __restrict__ out_log, float* __restrict__ out_soft,
                        int nrows) {
  __shared__ uint16_t hl[128][136];
  __shared__ float ssq[128][4];
  int wave = threadIdx.x >> 6, lane = threadIdx.x & 63;
  int n0 = lane & 15, quad = lane >> 4;
  int m0 = blockIdx.x * 128;
  const v8s z8 = {0, 0, 0, 0, 0, 0, 0, 0};

  int col0 = wave * 32 + n0;        // u = 0
  int col1 = wave * 32 + 16 + n0;   // u = 1

  // ---- stage: 128 A-rows -> hl (each wave its 32 rows, 16B/lane) ----
  {
    int chunk = lane & 15, rsub = lane >> 4;
#pragma unroll
    for (int it = 0; it < 8; it++) {
      int rl = wave * 32 + it * 4 + rsub;
      int row = m0 + rl;
      v8s v = (row < nrows)
            ? *reinterpret_cast<const v8s*>(A + (size_t)row * 128 + chunk * 8) : z8;
      *reinterpret_cast<v8s*>(&hl[rl][chunk * 8]) = v;
    }
  }
  __syncthreads();

  v4f acc[8][2];

  // ================= phase 1: tmp = relu(A @ W1^T + b1) =================
#pragma unroll
  for (int rt = 0; rt < 8; rt++)
#pragma unroll
    for (int u = 0; u < 2; u++) acc[rt][u] = {0.f, 0.f, 0.f, 0.f};
  {
    v8s wf[4][2];
#pragma unroll
    for (int kc = 0; kc < 4; kc++)
#pragma unroll
      for (int u = 0; u < 2; u++)
        wf[kc][u] = *reinterpret_cast<const v8s*>(
            W1rp + (size_t)kc * 4096 + (size_t)(wave * 2 + u) * 512 + (size_t)lane * 8);
#pragma unroll
    for (int kc = 0; kc < 4; kc++) {
#pragma unroll
      for (int rt = 0; rt < 8; rt++) {
        v8s a = *reinterpret_cast<const v8s*>(&hl[rt * 16 + n0][kc * 32 + quad * 8]);
        acc[rt][0] = __builtin_amdgcn_mfma_f32_16x16x32_bf16(a, wf[kc][0], acc[rt][0], 0, 0, 0);
        acc[rt][1] = __builtin_amdgcn_mfma_f32_16x16x32_bf16(a, wf[kc][1], acc[rt][1], 0, 0, 0);
      }
    }
  }
  __syncthreads();  // all waves done reading staged A
  {
    float bb0 = b1[col0], bb1 = b1[col1];
#pragma unroll
    for (int rt = 0; rt < 8; rt++)
#pragma unroll
      for (int r = 0; r < 4; r++) {
        int rl = rt * 16 + quad * 4 + r;
        hl[rl][col0] = f2b(fmaxf(acc[rt][0][r] + bb0, 0.f));
        hl[rl][col1] = f2b(fmaxf(acc[rt][1][r] + bb1, 0.f));
      }
  }
  __syncthreads();

  // ======= phase 2: xb = norm(relu(tmp @ W2^T + b2)) -> global + hl =======
#pragma unroll
  for (int rt = 0; rt < 8; rt++)
#pragma unroll
    for (int u = 0; u < 2; u++) acc[rt][u] = {0.f, 0.f, 0.f, 0.f};
  {
    v8s wf[4][2];
#pragma unroll
    for (int kc = 0; kc < 4; kc++)
#pragma unroll
      for (int u = 0; u < 2; u++)
        wf[kc][u] = *reinterpret_cast<const v8s*>(
            W2rp + (size_t)kc * 4096 + (size_t)(wave * 2 + u) * 512 + (size_t)lane * 8);
#pragma unroll
    for (int kc = 0; kc < 4; kc++) {
#pragma unroll
      for (int rt = 0; rt < 8; rt++) {
        v8s a = *reinterpret_cast<const v8s*>(&hl[rt * 16 + n0][kc * 32 + quad * 8]);
        acc[rt][0] = __builtin_amdgcn_mfma_f32_16x16x32_bf16(a, wf[kc][0], acc[rt][0], 0, 0, 0);
        acc[rt][1] = __builtin_amdgcn_mfma_f32_16x16x32_bf16(a, wf[kc][1], acc[rt][1], 0, 0, 0);
      }
    }
  }
  __syncthreads();  // all waves done reading tmp
  {
    float bb0 = b2[col0], bb1 = b2[col1];
    // relu in place + per-wave row partials
#pragma unroll
    for (int rt = 0; rt < 8; rt++) {
#pragma unroll
      for (int r = 0; r < 4; r++) {
        float v0 = fmaxf(acc[rt][0][r] + bb0, 0.f);
        float v1 = fmaxf(acc[rt][1][r] + bb1, 0.f);
        acc[rt][0][r] = v0;
        acc[rt][1][r] = v1;
        float ss = fmaf(v0, v0, v1 * v1);
        ss += __shfl_xor(ss, 1);
        ss += __shfl_xor(ss, 2);
        ss += __shfl_xor(ss, 4);
        ss += __shfl_xor(ss, 8);
        if (n0 == 0) ssq[rt * 16 + quad * 4 + r][wave] = ss;
      }
    }
  }
  __syncthreads();  // ssq visible
#pragma unroll
  for (int rt = 0; rt < 8; rt++) {
#pragma unroll
    for (int r = 0; r < 4; r++) {
      int rl = rt * 16 + quad * 4 + r;
      float s4 = ssq[rl][0] + ssq[rl][1] + ssq[rl][2] + ssq[rl][3];
      float sc = rsqrtf(1.f + s4);
      uint16_t h0 = f2b(acc[rt][0][r] * sc);
      uint16_t h1 = f2b(acc[rt][1][r] * sc);
      hl[rl][col0] = h0;
      hl[rl][col1] = h1;
      int row = m0 + rl;
      if (row < nrows) {
        xbout[(size_t)row * 128 + col0] = h0;
        xbout[(size_t)row * 128 + col1] = h1;
      }
    }
  }
  __syncthreads();

  // ============== phase 3: hid = relu(xb @ Wh^T + bh) -> hl ==============
#pragma unroll
  for (int rt = 0; rt < 8; rt++)
#pragma unroll
    for (int u = 0; u < 2; u++) acc[rt][u] = {0.f, 0.f, 0.f, 0.f};
  {
    v8s wf[4][2];
#pragma unroll
    for (int kc = 0; kc < 4; kc++)
#pragma unroll
      for (int u = 0; u < 2; u++)
        wf[kc][u] = *reinterpret_cast<const v8s*>(
            Whrp + (size_t)kc * 4096 + (size_t)(wave * 2 + u) * 512 + (size_t)lane * 8);
#pragma unroll
    for (int kc = 0; kc < 4; kc++) {
#pragma unroll
      for (int rt = 0; rt < 8; rt++) {
        v8s a = *reinterpret_cast<const v8s*>(&hl[rt * 16 + n0][kc * 32 + quad * 8]);
        acc[rt][0] = __builtin_amdgcn_mfma_f32_16x16x32_bf16(a, wf[kc][0], acc[rt][0], 0, 0, 0);
        acc[rt][1] = __builtin_amdgcn_mfma_f32_16x16x32_bf16(a, wf[kc][1], acc[rt][1], 0, 0, 0);
      }
    }
  }
  __syncthreads();  // all waves done reading xb
  {
    float bb0 = bh[col0], bb1 = bh[col1];
#pragma unroll
    for (int rt = 0; rt < 8; rt++)
#pragma unroll
      for (int r = 0; r < 4; r++) {
        int rl = rt * 16 + quad * 4 + r;
        hl[rl][col0] = f2b(fmaxf(acc[rt][0][r] + bb0, 0.f));
        hl[rl][col1] = f2b(fmaxf(acc[rt][1][r] + bb1, 0.f));
      }
  }
  __syncthreads();

  // ====== phase 4: head dot, 2 threads/row (split-K by dword parity) ======
  {
    int row = threadIdx.x >> 1;
    int s = threadIdx.x & 1;
    int node = m0 + row;
    float lg[C];
#pragma unroll
    for (int c = 0; c < C; c++) lg[c] = 0.f;
    const uint32_t* hr = reinterpret_cast<const uint32_t*>(&hl[row][0]);
#pragma unroll
    for (int j = 0; j < 32; j++) {
      uint32_t u = hr[j * 2 + s];
      float x0 = bf2f((uint16_t)u);
      float x1 = bf2f((uint16_t)(u >> 16));
      int k0 = 2 * (j * 2 + s);
#pragma unroll
      for (int c = 0; c < C; c++) lg[c] = fmaf(x0, w2[c * 128 + k0], lg[c]);
#pragma unroll
      for (int c = 0; c < C; c++) lg[c] = fmaf(x1, w2[c * 128 + k0 + 1], lg[c]);
    }
#pragma unroll
    for (int c = 0; c < C; c++) lg[c] += __shfl_xor(lg[c], 1);
    if (s == 0 && node < nrows) {
#pragma unroll
      for (int c = 0; c < C; c++) lg[c] += b2h[c];
      float m = lg[0];
#pragma unroll
      for (int c = 1; c < C; c++) m = fmaxf(m, lg[c]);
      float sum = 0.f;
      float e[C];
#pragma unroll
      for (int c = 0; c < C; c++) { e[c] = __expf(lg[c] - m); sum += e[c]; }
      float ls = __logf(sum);
      float inv = 1.f / sum;
#pragma unroll
      for (int c = 0; c < C; c++) {
        out_log[(size_t)node * C + c] = lg[c] - m - ls;
        out_soft[(size_t)node * C + c] = e[c] * inv;
      }
    }
  }
}

// ---------------- GRU: 8 waves, per-wave 16-col slice, weights in VGPR -----
__launch_bounds__(512, 2)
__global__ void k_gru8(const uint16_t* __restrict__ agg, const uint16_t* __restrict__ xb,
                       const uint16_t* __restrict__ Wrp,
                       const float* __restrict__ bih, const float* __restrict__ bhh,
                       uint16_t* __restrict__ hb, int n, int ntiles) {
  int wave = threadIdx.x >> 6, lane = threadIdx.x & 63;
  int n0 = lane & 15, quad = lane >> 4;
  int s = wave >> 1, u = wave & 1;
  const v8s z8 = {0, 0, 0, 0, 0, 0, 0, 0};

  v8s wf[24];  // [kc*6 + mat*3 + g]
#pragma unroll
  for (int kc = 0; kc < 4; kc++)
#pragma unroll
    for (int mat = 0; mat < 2; mat++)
#pragma unroll
      for (int g = 0; g < 3; g++)
        wf[kc * 6 + mat * 3 + g] = *reinterpret_cast<const v8s*>(
            Wrp + (size_t)((kc * 4 + s) * 12 + (u * 2 + mat) * 3 + g) * 512 +
            (size_t)lane * 8);

  int col = wave * 16 + n0;
  float bir = bih[col], biz = bih[128 + col], bin = bih[256 + col];
  float bhr = bhh[col], bhz = bhh[128 + col], bhn = bhh[256 + col];

  for (int tt = blockIdx.x; tt < ntiles; tt += gridDim.x) {
    int m0 = tt * 32;
    int r0 = m0 + n0, r1 = m0 + 16 + n0;
    bool ok0 = r0 < n, ok1 = r1 < n;

    v4f accI[2][3], accH[2][3];
#pragma unroll
    for (int rt = 0; rt < 2; rt++)
#pragma unroll
      for (int g = 0; g < 3; g++) {
        accI[rt][g] = {0.f, 0.f, 0.f, 0.f};
        accH[rt][g] = {0.f, 0.f, 0.f, 0.f};
      }

    const uint16_t* ap0 = agg + (size_t)r0 * 128 + quad * 8;
    const uint16_t* ap1 = agg + (size_t)r1 * 128 + quad * 8;
    const uint16_t* xp0 = xb + (size_t)r0 * 128 + quad * 8;
    const uint16_t* xp1 = xb + (size_t)r1 * 128 + quad * 8;
#pragma unroll
    for (int kc = 0; kc < 4; kc++) {
      v8s a0 = ok0 ? *reinterpret_cast<const v8s*>(ap0 + kc * 32) : z8;
      v8s a1 = ok1 ? *reinterpret_cast<const v8s*>(ap1 + kc * 32) : z8;
      v8s x0 = ok0 ? *reinterpret_cast<const v8s*>(xp0 + kc * 32) : z8;
      v8s x1 = ok1 ? *reinterpret_cast<const v8s*>(xp1 + kc * 32) : z8;
#pragma unroll
      for (int g = 0; g < 3; g++) {
        accI[0][g] = __builtin_amdgcn_mfma_f32_16x16x32_bf16(a0, wf[kc * 6 + g], accI[0][g], 0, 0, 0);
        accI[1][g] = __builtin_amdgcn_mfma_f32_16x16x32_bf16(a1, wf[kc * 6 + g], accI[1][g], 0, 0, 0);
        accH[0][g] = __builtin_amdgcn_mfma_f32_16x16x32_bf16(x0, wf[kc * 6 + 3 + g], accH[0][g], 0, 0, 0);
        accH[1][g] = __builtin_amdgcn_mfma_f32_16x16x32_bf16(x1, wf[kc * 6 + 3 + g], accH[1][g], 0, 0, 0);
      }
    }

#pragma unroll
    for (int rt = 0; rt < 2; rt++) {
#pragma unroll
      for (int r = 0; r < 4; r++) {
        int row = m0 + rt * 16 + quad * 4 + r;
        if (row < n) {
          float ir = accI[rt][0][r] + bir;
          float iz = accI[rt][1][r] + biz;
          float in_ = accI[rt][2][r] + bin;
          float hr = accH[rt][0][r] + bhr;
          float hz = accH[rt][1][r] + bhz;
          float hn = accH[rt][2][r] + bhn;
          float rr = sigmoidf_(ir + hr);
          float zz = sigmoidf_(iz + hz);
          float nn = tanhf_(fmaf(rr, hn, in_));
          float xv = bf2f(xb[(size_t)row * 128 + col]);
          hb[(size_t)row * 128 + col] = f2b(fmaf(zz, xv - nn, nn));
        }
      }
    }
  }
}

// ---------------------------------------------------------------------------
extern "C" void kernel_launch(void* const* d_in, const int* in_sizes, int n_in,
                              void* d_out, int out_size, void* d_ws, size_t ws_size,
                              hipStream_t stream) {
  const int N = in_sizes[0] / 128;   // 100000
  const int E = in_sizes[2];         // 1600000
  const int NB = (N + 127) >> 7;     // buckets of 128 nodes (782)

  static const int wn[18] = {16384, 128, 49152, 384, 49152, 384,
                             147456, 147456, 1152, 1152, 49152, 384,
                             256, 2, 768, 6, 2688, 21};
  CvtDesc cd;
  int off = 0;
  for (int i = 0; i < 18; i++) {
    cd.src[i] = d_in[3 + i];
    cd.off[i] = off;
    off += wn[i];
  }
  cd.off[18] = off;
  const int wtotal = off;  // 466077

  // ---- workspace bump allocator (~120 MB) ----
  char* p = (char*)d_ws;
  size_t used = 0;
  auto alloc = [&](size_t bytes) -> char* {
    char* r = p;
    size_t b = (bytes + 255) & ~(size_t)255;
    p += b;
    used += b;
    return r;
  };
  int*      flag    = (int*)alloc(256);
  float*    wbase   = (float*)alloc((size_t)wtotal * 4);
  uint16_t* wb16    = (uint16_t*)alloc((size_t)wtotal * 2);
  uint16_t* mmrp    = (uint16_t*)alloc((size_t)10 * 16384 * 2);      // repacked mm W
  uint16_t* grurp   = (uint16_t*)alloc((size_t)3 * 192 * 512 * 2);   // repacked gru W
  uint16_t* xb      = (uint16_t*)alloc((size_t)N * 128 * 2);
  uint16_t* aggb    = (uint16_t*)alloc((size_t)N * 128 * 2);         // feat / agg
  uint16_t* hb      = (uint16_t*)alloc((size_t)N * 128 * 2);         // GRU h
  int*      rowptr  = (int*)alloc((size_t)(N + 1) * 4);
  int*      gcur    = (int*)alloc((size_t)NB * 4);
  int*      bbase   = (int*)alloc((size_t)(NB + 1) * 4);
  uint2*    ep0     = (uint2*)alloc((size_t)NB * BUCKET_CAP * 8);    // bucket streams
  uint2*    epack   = (uint2*)alloc((size_t)E * 8);                  // CSR payload

  // FLOAT32 output layout (elements): log0|log1|log2|soft0|soft1|soft2
  float* out = (float*)d_out;
  float* outlog[3]  = {out, out + 2 * (size_t)N, out + 8 * (size_t)N};
  float* outsoft[3] = {out + 29 * (size_t)N, out + 31 * (size_t)N, out + 37 * (size_t)N};

  if (used > ws_size) {
    k_zero_f<<<(out_size + 255) / 256, 256, 0, stream>>>(out, out_size);
    return;
  }

  float* b1f   = wbase + cd.off[1];
  float* ginb1 = wbase + cd.off[3];
  float* ginb2 = wbase + cd.off[5];
  float* bih   = wbase + cd.off[8];
  float* bhh   = wbase + cd.off[9];
  float* hb1   = wbase + cd.off[11];
  float* hw2_0 = wbase + cd.off[12];
  float* hb2_0 = wbase + cd.off[13];
  float* hw2_1 = wbase + cd.off[14];
  float* hb2_1 = wbase + cd.off[15];
  float* hw2_2 = wbase + cd.off[16];
  float* hb2_2 = wbase + cd.off[17];

  uint16_t* w1b   = wb16 + cd.off[0];
  uint16_t* ginw1b= wb16 + cd.off[2];
  uint16_t* ginw2b= wb16 + cd.off[4];
  uint16_t* wihb  = wb16 + cd.off[6];
  uint16_t* whhb  = wb16 + cd.off[7];
  uint16_t* hw1b  = wb16 + cd.off[10];

  uint16_t* w1rp    = mmrp;
  uint16_t* ginw1rp = mmrp + (size_t)1 * 16384;
  uint16_t* ginw2rp = mmrp + (size_t)4 * 16384;
  uint16_t* hw1rp   = mmrp + (size_t)7 * 16384;

  const int* dst = (const int*)d_in[1];       // edge_index[0]
  const int* src = (const int*)d_in[1] + E;   // edge_index[1]

  // ---- dtype probe + conversions + repack ----
  k_detect<<<1, 64, 0, stream>>>((const uint32_t*)d_in[0], flag);
  k_cvtw<<<(wtotal + 255) / 256, 256, 0, stream>>>(cd, wbase, wb16, flag, wtotal);
  k_cvt_feat<<<((size_t)N * 128 + 255) / 256, 256, 0, stream>>>(d_in[0], aggb,
                                                                N * 128, flag);
  k_pack_mm<<<(1 * 2048 + 255) / 256, 256, 0, stream>>>(w1b, w1rp, 1);
  k_pack_mm<<<(3 * 2048 + 255) / 256, 256, 0, stream>>>(ginw1b, ginw1rp, 3);
  k_pack_mm<<<(3 * 2048 + 255) / 256, 256, 0, stream>>>(ginw2b, ginw2rp, 3);
  k_pack_mm<<<(3 * 2048 + 255) / 256, 256, 0, stream>>>(hw1b, hw1rp, 3);
  k_pack_gru<<<(3 * 192 * 64 + 255) / 256, 256, 0, stream>>>(wihb, whhb, grurp, 3);

  // ---- CSR build (chunk-reserved partition; line-granular writes) ----
  k_zero_i<<<(NB + 255) / 256, 256, 0, stream>>>(gcur, NB);
  k_part<<<256, 256, 0, stream>>>(dst, src, d_in[2], gcur, ep0, flag, E, NB);
  k_bprefix<<<1, 256, 0, stream>>>(gcur, bbase, NB);
  k_build<<<NB, 256, 0, stream>>>(ep0, gcur, bbase, rowptr, epack, N, NB);

  int mmrb = (N + 127) / 128;      // 128 rows/block
  int spb  = (N + 3) / 4;
  int ntiles32 = (N + 31) / 32;    // k_gru8 tiles

  // mlp1: xb = relu(features(aggb) @ w1^T + b1)
  k_mm<1><<<mmrb, 256, 0, stream>>>(aggb, w1rp, b1f, xb, N);

  for (int i = 0; i < 3; i++) {
    // aggb = spmm(xb)
    k_spmm<<<spb, 256, 0, stream>>>(xb, rowptr, epack, aggb, N);
    // hb = GRU(aggb, xb)  [weights in VGPR, persistent]
    k_gru8<<<256, 512, 0, stream>>>(aggb, xb, grurp + (size_t)i * 192 * 512,
                                    bih + i * 384, bhh + i * 384, hb, N, ntiles32);
    // fused: xb = norm(relu(relu(hb@ginw1+b)@ginw2+b)); heads from xb
    if (i == 0)
      k_mm12h<2><<<mmrb, 256, 0, stream>>>(hb, ginw1rp + (size_t)i * 16384,
                                           ginb1 + i * 128,
                                           ginw2rp + (size_t)i * 16384,
                                           ginb2 + i * 128,
                                           hw1rp + (size_t)i * 16384, hb1 + i * 128,
                                           hw2_0, hb2_0, xb,
                                           outlog[0], outsoft[0], N);
    else if (i == 1)
      k_mm12h<6><<<mmrb, 256, 0, stream>>>(hb, ginw1rp + (size_t)i * 16384,
                                           ginb1 + i * 128,
                                           ginw2rp + (size_t)i * 16384,
                                           ginb2 + i * 128,
                                           hw1rp + (size_t)i * 16384, hb1 + i * 128,
                                           hw2_1, hb2_1, xb,
                                           outlog[1], outsoft[1], N);
    else
      k_mm12h<21><<<mmrb, 256, 0, stream>>>(hb, ginw1rp + (size_t)i * 16384,
                                            ginb1 + i * 128,
                                            ginw2rp + (size_t)i * 16384,
                                            ginb2 + i * 128,
                                            hw1rp + (size_t)i * 16384, hb1 + i * 128,
                                            hw2_2, hb2_2, xb,
                                            outlog[2], outsoft[2], N);
  }
}

// Round 10
// 839.295 us; speedup vs baseline: 1.0471x; 1.0471x over previous
//
#include <hip/hip_runtime.h>
#include <cstdint>
#include <cstddef>

// ---------------------------------------------------------------------------
// GatedGIN forward. Inputs bf16-or-f32 (runtime probe), OUTPUT = FLOAT32.
// Round 21: GIN chain rebuilt gru8-style after r8/r9 falsified the
// "weight-load count" model; the real poison was the barrier-punctuated
// serial phase chain at ~3 blocks/CU. New: k_gin1 (col-split, weights in
// VGPR, persistent, 0 barriers) + k_g2h (persistent 512-thr blocks, W2/Wh/w2
// staged to LDS once, wave-PRIVATE 32-row tiles + private scratch, 0 barriers
// in loop: GEMM2+norm -> xb, GEMM3, head+softmax). k_mm12h deleted.
// ---------------------------------------------------------------------------

typedef short  v8s __attribute__((ext_vector_type(8)));
typedef float  v4f __attribute__((ext_vector_type(4)));

#define BUCKET_CAP 4096

static __device__ __forceinline__ float bf2f(uint16_t u) {
  return __uint_as_float(((uint32_t)u) << 16);
}
static __device__ __forceinline__ uint16_t f2b(float f) {
  uint32_t x = __float_as_uint(f);
  return (uint16_t)((x + 0x7FFFu + ((x >> 16) & 1u)) >> 16);
}
static __device__ __forceinline__ float sigmoidf_(float v) {
  return 1.f / (1.f + __expf(-v));
}
static __device__ __forceinline__ float tanhf_(float v) {
  return 1.f - 2.f / (__expf(2.f * v) + 1.f);
}

// ---------------- dtype probe ----------------
__global__ void k_detect(const uint32_t* __restrict__ u, int* __restrict__ flag) {
  int lane = threadIdx.x;  // 64 threads
  uint32_t low = u[lane] & 0xFFFFu;
  uint32_t e = (low >> 7) & 0xFFu;
  bool pass = (e == 0) || (e >= 110 && e <= 141);
  unsigned long long b = __ballot(pass);
  if (lane == 0) *flag = (__popcll(b) >= 32) ? 1 : 0;
}

// ---------------- weight convert: one pass -> f32 arena + bf16 arena -------
struct CvtDesc {
  const void* src[18];
  int off[19];
};

__global__ void k_cvtw(CvtDesc c, float* __restrict__ wbase,
                       uint16_t* __restrict__ wb16,
                       const int* __restrict__ flag, int total) {
  int gid = blockIdx.x * 256 + threadIdx.x;
  if (gid >= total) return;
  int t = 0;
#pragma unroll
  for (int i = 1; i < 18; i++)
    if (gid >= c.off[i]) t = i;
  int local = gid - c.off[t];
  float v;
  if (*flag) v = bf2f(((const uint16_t*)c.src[t])[local]);
  else       v = ((const float*)c.src[t])[local];
  wbase[gid] = v;
  wb16[gid] = f2b(v);
}

__global__ void k_cvt_feat(const void* __restrict__ src, uint16_t* __restrict__ dst,
                           int n, const int* __restrict__ flag) {
  int i = blockIdx.x * 256 + threadIdx.x;
  if (i >= n) return;
  if (*flag) dst[i] = ((const uint16_t*)src)[i];
  else       dst[i] = f2b(((const float*)src)[i]);
}

__global__ void k_zero_i(int* __restrict__ p, int n) {
  int i = blockIdx.x * 256 + threadIdx.x;
  if (i < n) p[i] = 0;
}

__global__ void k_zero_f(float* __restrict__ p, int n) {
  int i = blockIdx.x * 256 + threadIdx.x;
  if (i < n) p[i] = 0.f;
}

// ---------------- weight repack: fragment-major for 16x16x32 MFMA ----------
__global__ void k_pack_mm(const uint16_t* __restrict__ src, uint16_t* __restrict__ dst,
                          int nmat) {
  int id = blockIdx.x * 256 + threadIdx.x;
  if (id >= nmat * 2048) return;
  int mat = id >> 11;
  int rem = id & 2047;
  int blk = rem >> 6, lane = rem & 63;
  int kc = blk >> 3, t = blk & 7;
  int n0 = lane & 15, quad = lane >> 4;
  const uint16_t* s = src + (size_t)mat * 16384 + (size_t)(t * 16 + n0) * 128 + kc * 32 + quad * 8;
  uint16_t* d = dst + (size_t)id * 8;
  *reinterpret_cast<v8s*>(d) = *reinterpret_cast<const v8s*>(s);
}

// GRU layout: blk = (kc*4 + s)*12 + (u*2 + mat)*3 + g  (192 blocks/layer)
__global__ void k_pack_gru(const uint16_t* __restrict__ wih, const uint16_t* __restrict__ whh,
                           uint16_t* __restrict__ dst, int nlayer) {
  int id = blockIdx.x * 256 + threadIdx.x;
  if (id >= nlayer * 192 * 64) return;
  int lane = id & 63;
  int blk = (id >> 6) % 192;
  int layer = (id >> 6) / 192;
  int g = blk % 3;
  int mat = (blk / 3) % 2;
  int u = (blk / 6) % 2;
  int w = (blk / 12) % 4;
  int kc = blk / 48;
  int n0 = lane & 15, quad = lane >> 4;
  const uint16_t* base = (mat == 0 ? wih : whh) + (size_t)layer * 384 * 128;
  const uint16_t* s = base + (size_t)(g * 128 + w * 32 + u * 16 + n0) * 128 + kc * 32 + quad * 8;
  uint16_t* d = dst + ((size_t)layer * 192 + blk) * 512 + (size_t)lane * 8;
  *reinterpret_cast<v8s*>(d) = *reinterpret_cast<const v8s*>(s);
}

// ---------------- CSR build: chunk-reserved bucket partition ----------------
__global__ void k_part(const int* __restrict__ dst, const int* __restrict__ src,
                       const void* __restrict__ w, int* __restrict__ gcur,
                       uint2* __restrict__ ep0, const int* __restrict__ flag,
                       int E, int NB) {
  __shared__ int hist[1024];
  __shared__ int lbase[1024];
  int t = threadIdx.x;
  int CH = (E + gridDim.x - 1) / gridDim.x;
  int e0 = blockIdx.x * CH;
  int e1 = e0 + CH;
  if (e1 > E) e1 = E;
  for (int b = t; b < NB; b += 256) hist[b] = 0;
  __syncthreads();
  for (int e = e0 + t; e < e1; e += 256)
    atomicAdd(&hist[dst[e] >> 7], 1);
  __syncthreads();
  for (int b = t; b < NB; b += 256) {
    int c = hist[b];
    lbase[b] = c ? atomicAdd(&gcur[b], c) : 0;
    hist[b] = 0;  // becomes local cursor
  }
  __syncthreads();
  bool bf = (*flag) != 0;
  for (int e = e0 + t; e < e1; e += 256) {
    int d = dst[e];
    int b = d >> 7;
    int pos = lbase[b] + atomicAdd(&hist[b], 1);
    if (pos >= BUCKET_CAP) pos = BUCKET_CAP - 1;  // safety, never on bench input
    float wv = bf ? bf2f(((const uint16_t*)w)[e]) : ((const float*)w)[e];
    ep0[(size_t)b * BUCKET_CAP + pos] =
        make_uint2((uint32_t)src[e] | (((uint32_t)d & 127u) << 25),
                   __float_as_uint(wv));
  }
}

// exclusive scan over per-bucket totals -> bbase[NB] (single block)
__global__ void k_bprefix(const int* __restrict__ gcur, int* __restrict__ bbase,
                          int nbuckets) {
  __shared__ int red[256];
  int t = threadIdx.x;
  int chunk = (nbuckets + 255) >> 8;
  int beg = t * chunk;
  int end = beg + chunk;
  if (end > nbuckets) end = nbuckets;
  int s = 0;
  for (int b = beg; b < end; b++) {
    int c = gcur[b];
    if (c > BUCKET_CAP) c = BUCKET_CAP;
    bbase[b] = c;  // temp: per-bucket total
    s += c;
  }
  red[t] = s;
  __syncthreads();
  for (int off = 1; off < 256; off <<= 1) {
    int u = (t >= off) ? red[t - off] : 0;
    __syncthreads();
    red[t] += u;
    __syncthreads();
  }
  int run = red[t] - s;
  for (int b = beg; b < end; b++) {
    int tot = bbase[b];
    bbase[b] = run;
    run += tot;
  }
}

// one block per bucket: LDS histogram of local dst -> rowptr slice + place
__global__ void k_build(const uint2* __restrict__ ep0, const int* __restrict__ gcur,
                        const int* __restrict__ bbase, int* __restrict__ rowptr,
                        uint2* __restrict__ ep, int n, int nbuckets) {
  __shared__ int lcnt[128];
  __shared__ int lsc[128];
  int b = blockIdx.x, t = threadIdx.x;
  int cnt = gcur[b];
  if (cnt > BUCKET_CAP) cnt = BUCKET_CAP;
  if (t < 128) lcnt[t] = 0;
  __syncthreads();

  const uint2* sp = ep0 + (size_t)b * BUCKET_CAP;
  // pass 1: histogram local dst
  for (int p = t; p < cnt; p += 256)
    atomicAdd(&lcnt[sp[p].x >> 25], 1);
  __syncthreads();

  // inclusive scan of lcnt -> lsc
  if (t < 128) lsc[t] = lcnt[t];
  __syncthreads();
  for (int off = 1; off < 128; off <<= 1) {
    int v = 0;
    if (t < 128 && t >= off) v = lsc[t - off];
    __syncthreads();
    if (t < 128) lsc[t] += v;
    __syncthreads();
  }

  int base = bbase[b];
  if (t < 128) {
    int excl = lsc[t] - lcnt[t];
    int node = b * 128 + t;
    if (node < n) rowptr[node] = base + excl;
    lcnt[t] = base + excl;  // becomes cursor
  }
  if (b == nbuckets - 1 && t == 0) rowptr[n] = base + lsc[127];  // == E
  __syncthreads();

  // pass 2: place edges at exact CSR positions (contiguous output region)
  for (int p = t; p < cnt; p += 256) {
    uint2 v = sp[p];
    int pos = atomicAdd(&lcnt[v.x >> 25], 1);
    ep[pos] = make_uint2(v.x & 0x01FFFFFFu, v.y);
  }
}

// ---------------- SpMM gather: 4 nodes/block, 64 thr/node, unroll 8 --------
__global__ void k_spmm(const uint16_t* __restrict__ x, const int* __restrict__ rowptr,
                       const uint2* __restrict__ ep, uint16_t* __restrict__ agg, int n) {
  int node = blockIdx.x * 4 + (threadIdx.x >> 6);
  int lane = threadIdx.x & 63;
  if (node >= n) return;
  int p0 = rowptr[node], p1 = rowptr[node + 1];
  float a0 = 0.f, a1 = 0.f;
  const uint16_t* xc = x + (size_t)lane * 2;
  int p = p0;
  for (; p + 7 < p1; p += 8) {
    uint2 e0 = ep[p], e1 = ep[p + 1], e2 = ep[p + 2], e3 = ep[p + 3];
    uint2 e4 = ep[p + 4], e5 = ep[p + 5], e6 = ep[p + 6], e7 = ep[p + 7];
    uint32_t u0 = *reinterpret_cast<const uint32_t*>(xc + (size_t)e0.x * 128);
    uint32_t u1 = *reinterpret_cast<const uint32_t*>(xc + (size_t)e1.x * 128);
    uint32_t u2 = *reinterpret_cast<const uint32_t*>(xc + (size_t)e2.x * 128);
    uint32_t u3 = *reinterpret_cast<const uint32_t*>(xc + (size_t)e3.x * 128);
    uint32_t u4 = *reinterpret_cast<const uint32_t*>(xc + (size_t)e4.x * 128);
    uint32_t u5 = *reinterpret_cast<const uint32_t*>(xc + (size_t)e5.x * 128);
    uint32_t u6 = *reinterpret_cast<const uint32_t*>(xc + (size_t)e6.x * 128);
    uint32_t u7 = *reinterpret_cast<const uint32_t*>(xc + (size_t)e7.x * 128);
    float w0 = __uint_as_float(e0.y), w1 = __uint_as_float(e1.y);
    float w2 = __uint_as_float(e2.y), w3 = __uint_as_float(e3.y);
    float w4 = __uint_as_float(e4.y), w5 = __uint_as_float(e5.y);
    float w6 = __uint_as_float(e6.y), w7 = __uint_as_float(e7.y);
    a0 = fmaf(w0, bf2f((uint16_t)u0), a0);
    a1 = fmaf(w0, bf2f((uint16_t)(u0 >> 16)), a1);
    a0 = fmaf(w1, bf2f((uint16_t)u1), a0);
    a1 = fmaf(w1, bf2f((uint16_t)(u1 >> 16)), a1);
    a0 = fmaf(w2, bf2f((uint16_t)u2), a0);
    a1 = fmaf(w2, bf2f((uint16_t)(u2 >> 16)), a1);
    a0 = fmaf(w3, bf2f((uint16_t)u3), a0);
    a1 = fmaf(w3, bf2f((uint16_t)(u3 >> 16)), a1);
    a0 = fmaf(w4, bf2f((uint16_t)u4), a0);
    a1 = fmaf(w4, bf2f((uint16_t)(u4 >> 16)), a1);
    a0 = fmaf(w5, bf2f((uint16_t)u5), a0);
    a1 = fmaf(w5, bf2f((uint16_t)(u5 >> 16)), a1);
    a0 = fmaf(w6, bf2f((uint16_t)u6), a0);
    a1 = fmaf(w6, bf2f((uint16_t)(u6 >> 16)), a1);
    a0 = fmaf(w7, bf2f((uint16_t)u7), a0);
    a1 = fmaf(w7, bf2f((uint16_t)(u7 >> 16)), a1);
  }
  for (; p + 1 < p1; p += 2) {
    uint2 e0 = ep[p], e1 = ep[p + 1];
    uint32_t u0 = *reinterpret_cast<const uint32_t*>(xc + (size_t)e0.x * 128);
    uint32_t u1 = *reinterpret_cast<const uint32_t*>(xc + (size_t)e1.x * 128);
    float w0 = __uint_as_float(e0.y), w1 = __uint_as_float(e1.y);
    a0 = fmaf(w0, bf2f((uint16_t)u0), a0);
    a1 = fmaf(w0, bf2f((uint16_t)(u0 >> 16)), a1);
    a0 = fmaf(w1, bf2f((uint16_t)u1), a0);
    a1 = fmaf(w1, bf2f((uint16_t)(u1 >> 16)), a1);
  }
  for (; p < p1; p++) {
    uint2 e0 = ep[p];
    float w0 = __uint_as_float(e0.y);
    uint32_t u0 = *reinterpret_cast<const uint32_t*>(xc + (size_t)e0.x * 128);
    a0 = fmaf(w0, bf2f((uint16_t)u0), a0);
    a1 = fmaf(w0, bf2f((uint16_t)(u0 >> 16)), a1);
  }
  uint32_t packed = (uint32_t)f2b(a0) | ((uint32_t)f2b(a1) << 16);
  *reinterpret_cast<uint32_t*>(agg + (size_t)node * 128 + lane * 2) = packed;
}

// ---------------- MFMA matmul, repacked W, 32 rows/wave (mlp1 only) --------
template <int EPI>
__launch_bounds__(256)
__global__ void k_mm(const uint16_t* __restrict__ A, const uint16_t* __restrict__ Wrp,
                     const float* __restrict__ bias, uint16_t* __restrict__ C,
                     int nrows) {
  int wave = threadIdx.x >> 6, lane = threadIdx.x & 63;
  int n0 = lane & 15, quad = lane >> 4;
  int m0 = (blockIdx.x * 4 + wave) * 32;
  int r0 = m0 + n0, r1 = m0 + 16 + n0;
  bool ok0 = r0 < nrows, ok1 = r1 < nrows;
  const v8s z8 = {0, 0, 0, 0, 0, 0, 0, 0};

  v4f acc[2][8];
#pragma unroll
  for (int rt = 0; rt < 2; rt++)
#pragma unroll
    for (int t = 0; t < 8; t++) acc[rt][t] = {0.f, 0.f, 0.f, 0.f};

  const uint16_t* ap0 = A + (size_t)r0 * 128 + quad * 8;
  const uint16_t* ap1 = A + (size_t)r1 * 128 + quad * 8;
#pragma unroll
  for (int kc = 0; kc < 4; kc++) {
    v8s a0 = ok0 ? *reinterpret_cast<const v8s*>(ap0 + kc * 32) : z8;
    v8s a1 = ok1 ? *reinterpret_cast<const v8s*>(ap1 + kc * 32) : z8;
    const uint16_t* wp = Wrp + (size_t)kc * 4096 + (size_t)lane * 8;
#pragma unroll
    for (int t = 0; t < 8; t++) {
      v8s bf = *reinterpret_cast<const v8s*>(wp + t * 512);
      acc[0][t] = __builtin_amdgcn_mfma_f32_16x16x32_bf16(a0, bf, acc[0][t], 0, 0, 0);
      acc[1][t] = __builtin_amdgcn_mfma_f32_16x16x32_bf16(a1, bf, acc[1][t], 0, 0, 0);
    }
  }

#pragma unroll
  for (int rt = 0; rt < 2; rt++) {
    int mb = m0 + rt * 16;
    float vv[8][4];
#pragma unroll
    for (int t = 0; t < 8; t++) {
      float b = bias[t * 16 + n0];
#pragma unroll
      for (int r = 0; r < 4; r++) vv[t][r] = fmaxf(acc[rt][t][r] + b, 0.f);
    }
    if (EPI == 2) {
#pragma unroll
      for (int r = 0; r < 4; r++) {
        float ss = 0.f;
#pragma unroll
        for (int t = 0; t < 8; t++) ss = fmaf(vv[t][r], vv[t][r], ss);
        ss += __shfl_xor(ss, 1);
        ss += __shfl_xor(ss, 2);
        ss += __shfl_xor(ss, 4);
        ss += __shfl_xor(ss, 8);
        float sc = rsqrtf(1.f + ss);
#pragma unroll
        for (int t = 0; t < 8; t++) vv[t][r] *= sc;
      }
    }
#pragma unroll
    for (int r = 0; r < 4; r++) {
      int row = mb + quad * 4 + r;
      if (row >= nrows) continue;
#pragma unroll
      for (int t = 0; t < 8; t++)
        C[(size_t)row * 128 + t * 16 + n0] = f2b(vv[t][r]);
    }
  }
}

// ---------------- GIN mlp1: persistent, col-split, weights in VGPR ---------
// Wave w owns cols [16w, 16w+16); 4 frags (kc=0..3, t=w) in VGPR. 0 barriers.
__launch_bounds__(512, 2)
__global__ void k_gin1(const uint16_t* __restrict__ hb, const uint16_t* __restrict__ W1rp,
                       const float* __restrict__ b1, uint16_t* __restrict__ tmp,
                       int n, int ntiles) {
  int wave = threadIdx.x >> 6, lane = threadIdx.x & 63;
  int n0 = lane & 15, quad = lane >> 4;
  const v8s z8 = {0, 0, 0, 0, 0, 0, 0, 0};

  v8s wf[4];
#pragma unroll
  for (int kc = 0; kc < 4; kc++)
    wf[kc] = *reinterpret_cast<const v8s*>(
        W1rp + (size_t)(kc * 8 + wave) * 512 + (size_t)lane * 8);

  int col = wave * 16 + n0;
  float bb = b1[col];

  for (int tt = blockIdx.x; tt < ntiles; tt += gridDim.x) {
    int m0 = tt * 32;
    int r0 = m0 + n0, r1 = m0 + 16 + n0;
    bool ok0 = r0 < n, ok1 = r1 < n;
    v4f acc0 = {0.f, 0.f, 0.f, 0.f};
    v4f acc1 = {0.f, 0.f, 0.f, 0.f};
    const uint16_t* ap0 = hb + (size_t)r0 * 128 + quad * 8;
    const uint16_t* ap1 = hb + (size_t)r1 * 128 + quad * 8;
#pragma unroll
    for (int kc = 0; kc < 4; kc++) {
      v8s a0 = ok0 ? *reinterpret_cast<const v8s*>(ap0 + kc * 32) : z8;
      v8s a1 = ok1 ? *reinterpret_cast<const v8s*>(ap1 + kc * 32) : z8;
      acc0 = __builtin_amdgcn_mfma_f32_16x16x32_bf16(a0, wf[kc], acc0, 0, 0, 0);
      acc1 = __builtin_amdgcn_mfma_f32_16x16x32_bf16(a1, wf[kc], acc1, 0, 0, 0);
    }
#pragma unroll
    for (int r = 0; r < 4; r++) {
      int row0 = m0 + quad * 4 + r;
      int row1 = m0 + 16 + quad * 4 + r;
      if (row0 < n) tmp[(size_t)row0 * 128 + col] = f2b(fmaxf(acc0[r] + bb, 0.f));
      if (row1 < n) tmp[(size_t)row1 * 128 + col] = f2b(fmaxf(acc1[r] + bb, 0.f));
    }
  }
}

// ---------------- GIN mlp2+norm+head-mlp+head: persistent, wave-private ----
// 512 thr. Stage W2/Wh (64KB) + head w2 (C*128 f32) to LDS once (1 barrier).
// Then each WAVE processes whole 32-row tiles with a private [32][136]
// scratch. 0 barriers in the loop. GEMM order/norm/head math identical to
// previously verified kernels.
template <int C>
__launch_bounds__(512)
__global__ void k_g2h(const uint16_t* __restrict__ tmp,
                      const uint16_t* __restrict__ W2rp, const float* __restrict__ b2,
                      const uint16_t* __restrict__ Whrp, const float* __restrict__ bh,
                      const float* __restrict__ w2, const float* __restrict__ b2h,
                      uint16_t* __restrict__ xbout,
                      float* __restrict__ out_log, float* __restrict__ out_soft,
                      int n, int ntiles) {
  __shared__ uint16_t W2l[16384];
  __shared__ uint16_t Whl[16384];
  __shared__ float w2l[128 * C];
  __shared__ uint16_t sc[8][32][136];
  int tid = threadIdx.x;

  // ---- stage weights (once) ----
  for (int i = tid; i < 2048; i += 512)
    reinterpret_cast<v8s*>(W2l)[i] = reinterpret_cast<const v8s*>(W2rp)[i];
  for (int i = tid; i < 2048; i += 512)
    reinterpret_cast<v8s*>(Whl)[i] = reinterpret_cast<const v8s*>(Whrp)[i];
  for (int i = tid; i < 128 * C; i += 512) w2l[i] = w2[i];
  __syncthreads();

  int wave = tid >> 6, lane = tid & 63;
  int n0 = lane & 15, quad = lane >> 4;
  const v8s z8 = {0, 0, 0, 0, 0, 0, 0, 0};
  uint16_t (*scw)[136] = sc[wave];

  for (int tt = blockIdx.x * 8 + wave; tt < ntiles; tt += gridDim.x * 8) {
    int m0 = tt * 32;
    int r0 = m0 + n0, r1 = m0 + 16 + n0;
    bool ok0 = r0 < n, ok1 = r1 < n;

    // ---- GEMM2: xb_pre = tmp @ W2^T ----
    v4f acc[2][8];
#pragma unroll
    for (int rt = 0; rt < 2; rt++)
#pragma unroll
      for (int t = 0; t < 8; t++) acc[rt][t] = {0.f, 0.f, 0.f, 0.f};
    const uint16_t* ap0 = tmp + (size_t)r0 * 128 + quad * 8;
    const uint16_t* ap1 = tmp + (size_t)r1 * 128 + quad * 8;
#pragma unroll
    for (int kc = 0; kc < 4; kc++) {
      v8s a0 = ok0 ? *reinterpret_cast<const v8s*>(ap0 + kc * 32) : z8;
      v8s a1 = ok1 ? *reinterpret_cast<const v8s*>(ap1 + kc * 32) : z8;
#pragma unroll
      for (int t = 0; t < 8; t++) {
        v8s bf = *reinterpret_cast<const v8s*>(&W2l[(size_t)(kc * 8 + t) * 512 + (size_t)lane * 8]);
        acc[0][t] = __builtin_amdgcn_mfma_f32_16x16x32_bf16(a0, bf, acc[0][t], 0, 0, 0);
        acc[1][t] = __builtin_amdgcn_mfma_f32_16x16x32_bf16(a1, bf, acc[1][t], 0, 0, 0);
      }
    }

    // ---- bias + relu + row-norm (wave-local) -> xbout + scratch ----
#pragma unroll
    for (int rt = 0; rt < 2; rt++) {
      float vv[8][4];
#pragma unroll
      for (int t = 0; t < 8; t++) {
        float b = b2[t * 16 + n0];
#pragma unroll
        for (int r = 0; r < 4; r++) vv[t][r] = fmaxf(acc[rt][t][r] + b, 0.f);
      }
#pragma unroll
      for (int r = 0; r < 4; r++) {
        float ss = 0.f;
#pragma unroll
        for (int t = 0; t < 8; t++) ss = fmaf(vv[t][r], vv[t][r], ss);
        ss += __shfl_xor(ss, 1);
        ss += __shfl_xor(ss, 2);
        ss += __shfl_xor(ss, 4);
        ss += __shfl_xor(ss, 8);
        float scn = rsqrtf(1.f + ss);
#pragma unroll
        for (int t = 0; t < 8; t++) vv[t][r] *= scn;
      }
#pragma unroll
      for (int r = 0; r < 4; r++) {
        int rl = rt * 16 + quad * 4 + r;
        int row = m0 + rl;
#pragma unroll
        for (int t = 0; t < 8; t++) {
          uint16_t hv = f2b(vv[t][r]);
          scw[rl][t * 16 + n0] = hv;
          if (row < n) xbout[(size_t)row * 128 + t * 16 + n0] = hv;
        }
      }
    }

    // ---- GEMM3: hid = relu(xb @ Wh^T + bh) -> scratch ----
    v4f acc3[2][8];
#pragma unroll
    for (int rt = 0; rt < 2; rt++)
#pragma unroll
      for (int t = 0; t < 8; t++) acc3[rt][t] = {0.f, 0.f, 0.f, 0.f};
#pragma unroll
    for (int kc = 0; kc < 4; kc++) {
      v8s a0 = *reinterpret_cast<const v8s*>(&scw[n0][kc * 32 + quad * 8]);
      v8s a1 = *reinterpret_cast<const v8s*>(&scw[16 + n0][kc * 32 + quad * 8]);
#pragma unroll
      for (int t = 0; t < 8; t++) {
        v8s bf = *reinterpret_cast<const v8s*>(&Whl[(size_t)(kc * 8 + t) * 512 + (size_t)lane * 8]);
        acc3[0][t] = __builtin_amdgcn_mfma_f32_16x16x32_bf16(a0, bf, acc3[0][t], 0, 0, 0);
        acc3[1][t] = __builtin_amdgcn_mfma_f32_16x16x32_bf16(a1, bf, acc3[1][t], 0, 0, 0);
      }
    }
#pragma unroll
    for (int rt = 0; rt < 2; rt++) {
#pragma unroll
      for (int t = 0; t < 8; t++) {
        float b = bh[t * 16 + n0];
#pragma unroll
        for (int r = 0; r < 4; r++) {
          int rl = rt * 16 + quad * 4 + r;
          scw[rl][t * 16 + n0] = f2b(fmaxf(acc3[rt][t][r] + b, 0.f));
        }
      }
    }

    // ---- head: 2 lanes/row (split-K by dword parity), softmax, f32 out ----
    {
      int rowl = lane >> 1;
      int s = lane & 1;
      int node = m0 + rowl;
      float lg[C];
#pragma unroll
      for (int c = 0; c < C; c++) lg[c] = 0.f;
      const uint32_t* hr = reinterpret_cast<const uint32_t*>(&scw[rowl][0]);
#pragma unroll
      for (int j = 0; j < 32; j++) {
        uint32_t u = hr[j * 2 + s];
        float x0 = bf2f((uint16_t)u);
        float x1 = bf2f((uint16_t)(u >> 16));
        int k0 = 2 * (j * 2 + s);
#pragma unroll
        for (int c = 0; c < C; c++) lg[c] = fmaf(x0, w2l[c * 128 + k0], lg[c]);
#pragma unroll
        for (int c = 0; c < C; c++) lg[c] = fmaf(x1, w2l[c * 128 + k0 + 1], lg[c]);
      }
#pragma unroll
      for (int c = 0; c < C; c++) lg[c] += __shfl_xor(lg[c], 1);
      if (s == 0 && node < n) {
#pragma unroll
        for (int c = 0; c < C; c++) lg[c] += b2h[c];
        float m = lg[0];
#pragma unroll
        for (int c = 1; c < C; c++) m = fmaxf(m, lg[c]);
        float sum = 0.f;
        float e[C];
#pragma unroll
        for (int c = 0; c < C; c++) { e[c] = __expf(lg[c] - m); sum += e[c]; }
        float ls = __logf(sum);
        float inv = 1.f / sum;
#pragma unroll
        for (int c = 0; c < C; c++) {
          out_log[(size_t)node * C + c] = lg[c] - m - ls;
          out_soft[(size_t)node * C + c] = e[c] * inv;
        }
      }
    }
  }
}

// ---------------- GRU: 8 waves, per-wave 16-col slice, weights in VGPR -----
__launch_bounds__(512, 2)
__global__ void k_gru8(const uint16_t* __restrict__ agg, const uint16_t* __restrict__ xb,
                       const uint16_t* __restrict__ Wrp,
                       const float* __restrict__ bih, const float* __restrict__ bhh,
                       uint16_t* __restrict__ hb, int n, int ntiles) {
  int wave = threadIdx.x >> 6, lane = threadIdx.x & 63;
  int n0 = lane & 15, quad = lane >> 4;
  int s = wave >> 1, u = wave & 1;
  const v8s z8 = {0, 0, 0, 0, 0, 0, 0, 0};

  v8s wf[24];  // [kc*6 + mat*3 + g]
#pragma unroll
  for (int kc = 0; kc < 4; kc++)
#pragma unroll
    for (int mat = 0; mat < 2; mat++)
#pragma unroll
      for (int g = 0; g < 3; g++)
        wf[kc * 6 + mat * 3 + g] = *reinterpret_cast<const v8s*>(
            Wrp + (size_t)((kc * 4 + s) * 12 + (u * 2 + mat) * 3 + g) * 512 +
            (size_t)lane * 8);

  int col = wave * 16 + n0;
  float bir = bih[col], biz = bih[128 + col], bin = bih[256 + col];
  float bhr = bhh[col], bhz = bhh[128 + col], bhn = bhh[256 + col];

  for (int tt = blockIdx.x; tt < ntiles; tt += gridDim.x) {
    int m0 = tt * 32;
    int r0 = m0 + n0, r1 = m0 + 16 + n0;
    bool ok0 = r0 < n, ok1 = r1 < n;

    v4f accI[2][3], accH[2][3];
#pragma unroll
    for (int rt = 0; rt < 2; rt++)
#pragma unroll
      for (int g = 0; g < 3; g++) {
        accI[rt][g] = {0.f, 0.f, 0.f, 0.f};
        accH[rt][g] = {0.f, 0.f, 0.f, 0.f};
      }

    const uint16_t* ap0 = agg + (size_t)r0 * 128 + quad * 8;
    const uint16_t* ap1 = agg + (size_t)r1 * 128 + quad * 8;
    const uint16_t* xp0 = xb + (size_t)r0 * 128 + quad * 8;
    const uint16_t* xp1 = xb + (size_t)r1 * 128 + quad * 8;
#pragma unroll
    for (int kc = 0; kc < 4; kc++) {
      v8s a0 = ok0 ? *reinterpret_cast<const v8s*>(ap0 + kc * 32) : z8;
      v8s a1 = ok1 ? *reinterpret_cast<const v8s*>(ap1 + kc * 32) : z8;
      v8s x0 = ok0 ? *reinterpret_cast<const v8s*>(xp0 + kc * 32) : z8;
      v8s x1 = ok1 ? *reinterpret_cast<const v8s*>(xp1 + kc * 32) : z8;
#pragma unroll
      for (int g = 0; g < 3; g++) {
        accI[0][g] = __builtin_amdgcn_mfma_f32_16x16x32_bf16(a0, wf[kc * 6 + g], accI[0][g], 0, 0, 0);
        accI[1][g] = __builtin_amdgcn_mfma_f32_16x16x32_bf16(a1, wf[kc * 6 + g], accI[1][g], 0, 0, 0);
        accH[0][g] = __builtin_amdgcn_mfma_f32_16x16x32_bf16(x0, wf[kc * 6 + 3 + g], accH[0][g], 0, 0, 0);
        accH[1][g] = __builtin_amdgcn_mfma_f32_16x16x32_bf16(x1, wf[kc * 6 + 3 + g], accH[1][g], 0, 0, 0);
      }
    }

#pragma unroll
    for (int rt = 0; rt < 2; rt++) {
#pragma unroll
      for (int r = 0; r < 4; r++) {
        int row = m0 + rt * 16 + quad * 4 + r;
        if (row < n) {
          float ir = accI[rt][0][r] + bir;
          float iz = accI[rt][1][r] + biz;
          float in_ = accI[rt][2][r] + bin;
          float hr = accH[rt][0][r] + bhr;
          float hz = accH[rt][1][r] + bhz;
          float hn = accH[rt][2][r] + bhn;
          float rr = sigmoidf_(ir + hr);
          float zz = sigmoidf_(iz + hz);
          float nn = tanhf_(fmaf(rr, hn, in_));
          float xv = bf2f(xb[(size_t)row * 128 + col]);
          hb[(size_t)row * 128 + col] = f2b(fmaf(zz, xv - nn, nn));
        }
      }
    }
  }
}

// ---------------------------------------------------------------------------
extern "C" void kernel_launch(void* const* d_in, const int* in_sizes, int n_in,
                              void* d_out, int out_size, void* d_ws, size_t ws_size,
                              hipStream_t stream) {
  const int N = in_sizes[0] / 128;   // 100000
  const int E = in_sizes[2];         // 1600000
  const int NB = (N + 127) >> 7;     // buckets of 128 nodes (782)

  static const int wn[18] = {16384, 128, 49152, 384, 49152, 384,
                             147456, 147456, 1152, 1152, 49152, 384,
                             256, 2, 768, 6, 2688, 21};
  CvtDesc cd;
  int off = 0;
  for (int i = 0; i < 18; i++) {
    cd.src[i] = d_in[3 + i];
    cd.off[i] = off;
    off += wn[i];
  }
  cd.off[18] = off;
  const int wtotal = off;  // 466077

  // ---- workspace bump allocator (~120 MB) ----
  char* p = (char*)d_ws;
  size_t used = 0;
  auto alloc = [&](size_t bytes) -> char* {
    char* r = p;
    size_t b = (bytes + 255) & ~(size_t)255;
    p += b;
    used += b;
    return r;
  };
  int*      flag    = (int*)alloc(256);
  float*    wbase   = (float*)alloc((size_t)wtotal * 4);
  uint16_t* wb16    = (uint16_t*)alloc((size_t)wtotal * 2);
  uint16_t* mmrp    = (uint16_t*)alloc((size_t)10 * 16384 * 2);      // repacked mm W
  uint16_t* grurp   = (uint16_t*)alloc((size_t)3 * 192 * 512 * 2);   // repacked gru W
  uint16_t* xb      = (uint16_t*)alloc((size_t)N * 128 * 2);
  uint16_t* aggb    = (uint16_t*)alloc((size_t)N * 128 * 2);         // feat / agg / tmp
  uint16_t* hb      = (uint16_t*)alloc((size_t)N * 128 * 2);         // GRU h
  int*      rowptr  = (int*)alloc((size_t)(N + 1) * 4);
  int*      gcur    = (int*)alloc((size_t)NB * 4);
  int*      bbase   = (int*)alloc((size_t)(NB + 1) * 4);
  uint2*    ep0     = (uint2*)alloc((size_t)NB * BUCKET_CAP * 8);    // bucket streams
  uint2*    epack   = (uint2*)alloc((size_t)E * 8);                  // CSR payload

  // FLOAT32 output layout (elements): log0|log1|log2|soft0|soft1|soft2
  float* out = (float*)d_out;
  float* outlog[3]  = {out, out + 2 * (size_t)N, out + 8 * (size_t)N};
  float* outsoft[3] = {out + 29 * (size_t)N, out + 31 * (size_t)N, out + 37 * (size_t)N};

  if (used > ws_size) {
    k_zero_f<<<(out_size + 255) / 256, 256, 0, stream>>>(out, out_size);
    return;
  }

  float* b1f   = wbase + cd.off[1];
  float* ginb1 = wbase + cd.off[3];
  float* ginb2 = wbase + cd.off[5];
  float* bih   = wbase + cd.off[8];
  float* bhh   = wbase + cd.off[9];
  float* hb1   = wbase + cd.off[11];
  float* hw2_0 = wbase + cd.off[12];
  float* hb2_0 = wbase + cd.off[13];
  float* hw2_1 = wbase + cd.off[14];
  float* hb2_1 = wbase + cd.off[15];
  float* hw2_2 = wbase + cd.off[16];
  float* hb2_2 = wbase + cd.off[17];

  uint16_t* w1b   = wb16 + cd.off[0];
  uint16_t* ginw1b= wb16 + cd.off[2];
  uint16_t* ginw2b= wb16 + cd.off[4];
  uint16_t* wihb  = wb16 + cd.off[6];
  uint16_t* whhb  = wb16 + cd.off[7];
  uint16_t* hw1b  = wb16 + cd.off[10];

  uint16_t* w1rp    = mmrp;
  uint16_t* ginw1rp = mmrp + (size_t)1 * 16384;
  uint16_t* ginw2rp = mmrp + (size_t)4 * 16384;
  uint16_t* hw1rp   = mmrp + (size_t)7 * 16384;

  const int* dst = (const int*)d_in[1];       // edge_index[0]
  const int* src = (const int*)d_in[1] + E;   // edge_index[1]

  // ---- dtype probe + conversions + repack ----
  k_detect<<<1, 64, 0, stream>>>((const uint32_t*)d_in[0], flag);
  k_cvtw<<<(wtotal + 255) / 256, 256, 0, stream>>>(cd, wbase, wb16, flag, wtotal);
  k_cvt_feat<<<((size_t)N * 128 + 255) / 256, 256, 0, stream>>>(d_in[0], aggb,
                                                                N * 128, flag);
  k_pack_mm<<<(1 * 2048 + 255) / 256, 256, 0, stream>>>(w1b, w1rp, 1);
  k_pack_mm<<<(3 * 2048 + 255) / 256, 256, 0, stream>>>(ginw1b, ginw1rp, 3);
  k_pack_mm<<<(3 * 2048 + 255) / 256, 256, 0, stream>>>(ginw2b, ginw2rp, 3);
  k_pack_mm<<<(3 * 2048 + 255) / 256, 256, 0, stream>>>(hw1b, hw1rp, 3);
  k_pack_gru<<<(3 * 192 * 64 + 255) / 256, 256, 0, stream>>>(wihb, whhb, grurp, 3);

  // ---- CSR build (chunk-reserved partition; line-granular writes) ----
  k_zero_i<<<(NB + 255) / 256, 256, 0, stream>>>(gcur, NB);
  k_part<<<256, 256, 0, stream>>>(dst, src, d_in[2], gcur, ep0, flag, E, NB);
  k_bprefix<<<1, 256, 0, stream>>>(gcur, bbase, NB);
  k_build<<<NB, 256, 0, stream>>>(ep0, gcur, bbase, rowptr, epack, N, NB);

  int mmrb = (N + 127) / 128;      // 128 rows/block (k_mm)
  int spb  = (N + 3) / 4;
  int ntiles32 = (N + 31) / 32;    // 32-row tiles

  // mlp1: xb = relu(features(aggb) @ w1^T + b1)
  k_mm<1><<<mmrb, 256, 0, stream>>>(aggb, w1rp, b1f, xb, N);

  for (int i = 0; i < 3; i++) {
    // aggb = spmm(xb)
    k_spmm<<<spb, 256, 0, stream>>>(xb, rowptr, epack, aggb, N);
    // hb = GRU(aggb, xb)  [weights in VGPR, persistent]
    k_gru8<<<256, 512, 0, stream>>>(aggb, xb, grurp + (size_t)i * 192 * 512,
                                    bih + i * 384, bhh + i * 384, hb, N, ntiles32);
    // aggb(tmp) = relu(hb @ ginw1^T + ginb1)  [persistent, col-split]
    k_gin1<<<256, 512, 0, stream>>>(hb, ginw1rp + (size_t)i * 16384,
                                    ginb1 + i * 128, aggb, N, ntiles32);
    // xb = norm(relu(aggb @ ginw2^T + ginb2)); heads  [persistent, wave-private]
    if (i == 0)
      k_g2h<2><<<256, 512, 0, stream>>>(aggb, ginw2rp + (size_t)i * 16384,
                                        ginb2 + i * 128,
                                        hw1rp + (size_t)i * 16384, hb1 + i * 128,
                                        hw2_0, hb2_0, xb,
                                        outlog[0], outsoft[0], N, ntiles32);
    else if (i == 1)
      k_g2h<6><<<256, 512, 0, stream>>>(aggb, ginw2rp + (size_t)i * 16384,
                                        ginb2 + i * 128,
                                        hw1rp + (size_t)i * 16384, hb1 + i * 128,
                                        hw2_1, hb2_1, xb,
                                        outlog[1], outsoft[1], N, ntiles32);
    else
      k_g2h<21><<<256, 512, 0, stream>>>(aggb, ginw2rp + (size_t)i * 16384,
                                         ginb2 + i * 128,
                                         hw1rp + (size_t)i * 16384, hb1 + i * 128,
                                         hw2_2, hb2_2, xb,
                                         outlog[2], outsoft[2], N, ntiles32);
  }
}